// Round 1
// baseline (982.822 us; speedup 1.0000x reference)
//
#include <hip/hip_runtime.h>
#include <hip/hip_bf16.h>

// Problem constants (fixed by reference)
#define SEQ    2048
#define BATCH  2
#define MROWS  (SEQ*BATCH)    // 4096
#define EMBED  1024
#define KCTX   3
#define XDIM   (KCTX*EMBED)   // 3072
#define VOCAB  50257
#define VPAD   50304          // 393*128, multiple of 128

using u16 = unsigned short;
typedef __attribute__((ext_vector_type(8))) short   frag_ab;  // 8 bf16 (4 VGPRs)
typedef __attribute__((ext_vector_type(4))) float   frag_cd;  // 4 f32 acc

__device__ __forceinline__ u16 f2bf(float f) {
  union { float f; unsigned u; } v; v.f = f;
  unsigned r = v.u + 0x7fffu + ((v.u >> 16) & 1u);  // round-to-nearest-even
  return (u16)(r >> 16);
}

// ---------------------------------------------------------------------------
// Gather: XB[r][i*1024+c] = bf16(E[tok(r,i)][c]); r = s*BATCH+b
// window i: t = s + i - (KCTX-1); t<0 -> token 0
// ---------------------------------------------------------------------------
__global__ void gather_x(const int* __restrict__ tokens,
                         const float* __restrict__ E,
                         u16* __restrict__ XB) {
  const int r = blockIdx.x;          // 0..4095
  const int s = r >> 1, b = r & 1;
  #pragma unroll
  for (int i = 0; i < KCTX; ++i) {
    int t = s + i - (KCTX - 1);
    int tok = (t >= 0) ? tokens[t * BATCH + b] : 0;
    const float* src = &E[(size_t)tok * EMBED];
    u16* dst = &XB[(size_t)r * XDIM + i * EMBED];
    int c = threadIdx.x * 4;                       // 256 threads * 4 = 1024
    float4 v = *(const float4*)&src[c];
    u16 o[4] = { f2bf(v.x), f2bf(v.y), f2bf(v.z), f2bf(v.w) };
    *(ulong1*)&dst[c] = *(ulong1*)o;               // 8B store
  }
}

// ---------------------------------------------------------------------------
// Transpose + f32->bf16: W (K x N) -> WT (Npad x K). n >= N writes 0.
// grid: (Npad/32, K/32), block 256
// ---------------------------------------------------------------------------
__global__ void transpose_cvt(const float* __restrict__ W,
                              u16* __restrict__ WT,
                              int K, int N) {
  __shared__ float tile[32][33];
  const int nb = blockIdx.x * 32, kb = blockIdx.y * 32;
  const int tx = threadIdx.x & 31, ty = threadIdx.x >> 5;  // ty 0..7
  #pragma unroll
  for (int i = 0; i < 32; i += 8) {
    int k = kb + ty + i, n = nb + tx;
    tile[ty + i][tx] = (n < N) ? W[(size_t)k * N + n] : 0.f;
  }
  __syncthreads();
  #pragma unroll
  for (int i = 0; i < 32; i += 8) {
    int n = nb + ty + i, k = kb + tx;
    WT[(size_t)n * K + k] = f2bf(tile[tx][ty + i]);
  }
}

// ---------------------------------------------------------------------------
// GEMM: C[m][n] = sum_k A[m][k]*BT[n][k] (+bias, epilogue)
// A: M x K bf16 row-major; BT: Ngrid x K bf16 row-major (Ngrid = gridDim.x*128)
// EPI=0: silu(acc+bias) -> bf16, Nout cols (no guard; N multiple of 128)
// EPI=1: acc+bias -> f32, store only col < Nout
// 128x128 tile, BK=64, 4 waves (2x2), 64x64 per wave, mfma 16x16x32 bf16.
// ---------------------------------------------------------------------------
template<int EPI>
__global__ __launch_bounds__(256, 2)
void gemm_bt(const u16* __restrict__ A, const u16* __restrict__ BT,
             const float* __restrict__ bias, void* __restrict__ Cout,
             int K, int Nout) {
  __shared__ u16 lA[128 * 64];
  __shared__ u16 lB[128 * 64];
  const int tid  = threadIdx.x;
  const int wave = tid >> 6, lane = tid & 63;
  const int m0 = blockIdx.y * 128;
  const int n0 = blockIdx.x * 128;
  const int wm = (wave >> 1) * 64;
  const int wn = (wave & 1) * 64;

  frag_cd acc[4][4];
  #pragma unroll
  for (int i = 0; i < 4; ++i)
    #pragma unroll
    for (int j = 0; j < 4; ++j)
      acc[i][j] = (frag_cd)0.f;

  const int srow = lane >> 3;          // 0..7 within 8-row chunk
  const int skc  = (lane & 7) * 8;     // k element offset (16B granule)

  for (int k0 = 0; k0 < K; k0 += 64) {
    // stage A-tile and BT-tile (each 128x64 bf16 = 16KB) via global_load_lds x16
    #pragma unroll
    for (int i = 0; i < 4; ++i) {
      int chunk = wave * 4 + i;        // 0..15 -> 8 rows each
      int r = chunk * 8 + srow;
      const u16* ga = &A [(size_t)(m0 + r) * K + k0 + skc];
      const u16* gb = &BT[(size_t)(n0 + r) * K + k0 + skc];
      __builtin_amdgcn_global_load_lds(
          (const __attribute__((address_space(1))) void*)ga,
          (__attribute__((address_space(3))) void*)&lA[chunk * 512 + lane * 8],
          16, 0, 0);
      __builtin_amdgcn_global_load_lds(
          (const __attribute__((address_space(1))) void*)gb,
          (__attribute__((address_space(3))) void*)&lB[chunk * 512 + lane * 8],
          16, 0, 0);
    }
    __syncthreads();   // compiler drains vmcnt before barrier

    #pragma unroll
    for (int kk = 0; kk < 2; ++kk) {
      const int ko = kk * 32 + (lane >> 4) * 8;
      frag_ab af[4], bfr[4];
      #pragma unroll
      for (int i = 0; i < 4; ++i) {
        af[i]  = *(const frag_ab*)&lA[(wm + i * 16 + (lane & 15)) * 64 + ko];
        bfr[i] = *(const frag_ab*)&lB[(wn + i * 16 + (lane & 15)) * 64 + ko];
      }
      #pragma unroll
      for (int i = 0; i < 4; ++i)
        #pragma unroll
        for (int j = 0; j < 4; ++j)
          acc[i][j] = __builtin_amdgcn_mfma_f32_16x16x32_bf16(
              af[i], bfr[j], acc[i][j], 0, 0, 0);
    }
    __syncthreads();
  }

  // Epilogue. C/D layout: col = lane&15, row = (lane>>4)*4 + t  [verified m89]
  const int cr = (lane >> 4) * 4;
  const int cc = lane & 15;
  if (EPI == 0) {
    u16* H = (u16*)Cout;
    #pragma unroll
    for (int j = 0; j < 4; ++j) {
      int colg = n0 + wn + j * 16 + cc;
      float bv = bias[colg];
      #pragma unroll
      for (int i = 0; i < 4; ++i) {
        #pragma unroll
        for (int t = 0; t < 4; ++t) {
          int rowg = m0 + wm + i * 16 + cr + t;
          float v = acc[i][j][t] + bv;
          v = v / (1.f + __expf(-v));          // silu
          H[(size_t)rowg * Nout + colg] = f2bf(v);
        }
      }
    }
  } else {
    float* O = (float*)Cout;
    #pragma unroll
    for (int j = 0; j < 4; ++j) {
      int colg = n0 + wn + j * 16 + cc;
      if (colg < Nout) {
        float bv = bias[colg];
        #pragma unroll
        for (int i = 0; i < 4; ++i) {
          #pragma unroll
          for (int t = 0; t < 4; ++t) {
            int rowg = m0 + wm + i * 16 + cr + t;
            O[(size_t)rowg * Nout + colg] = acc[i][j][t] + bv;
          }
        }
      }
    }
  }
}

// ---------------------------------------------------------------------------
extern "C" void kernel_launch(void* const* d_in, const int* in_sizes, int n_in,
                              void* d_out, int out_size, void* d_ws, size_t ws_size,
                              hipStream_t stream) {
  const int*   tokens = (const int*)  d_in[0];   // (SEQ, BATCH) int32
  const float* E      = (const float*)d_in[1];   // (VOCAB, EMBED)
  const float* W1     = (const float*)d_in[2];   // (XDIM, EMBED)
  const float* b1     = (const float*)d_in[3];
  const float* W2     = (const float*)d_in[4];   // (EMBED, EMBED)
  const float* b2     = (const float*)d_in[5];
  const float* Wout   = (const float*)d_in[6];   // (EMBED, VOCAB)
  const float* bout   = (const float*)d_in[7];
  float* out = (float*)d_out;                    // (MROWS, VOCAB) f32

  // Workspace layout (~153.4 MB total)
  char* p = (char*)d_ws;
  u16* XB  = (u16*)p; p += (size_t)MROWS * XDIM  * 2;   // 25.2 MB
  u16* W1T = (u16*)p; p += (size_t)EMBED * XDIM  * 2;   //  6.3 MB
  u16* W2T = (u16*)p; p += (size_t)EMBED * EMBED * 2;   //  2.1 MB
  u16* WOT = (u16*)p; p += (size_t)VPAD  * EMBED * 2;   // 103.0 MB
  u16* H1  = (u16*)p; p += (size_t)MROWS * EMBED * 2;   //  8.4 MB
  u16* H2  = (u16*)p; p += (size_t)MROWS * EMBED * 2;   //  8.4 MB

  gather_x<<<MROWS, 256, 0, stream>>>(tokens, E, XB);
  transpose_cvt<<<dim3(EMBED/32, XDIM/32),  256, 0, stream>>>(W1,   W1T, XDIM,  EMBED);
  transpose_cvt<<<dim3(EMBED/32, EMBED/32), 256, 0, stream>>>(W2,   W2T, EMBED, EMBED);
  transpose_cvt<<<dim3(VPAD/32,  EMBED/32), 256, 0, stream>>>(Wout, WOT, EMBED, VOCAB);

  gemm_bt<0><<<dim3(EMBED/128, MROWS/128), 256, 0, stream>>>(XB, W1T, b1, H1, XDIM,  EMBED);
  gemm_bt<0><<<dim3(EMBED/128, MROWS/128), 256, 0, stream>>>(H1, W2T, b2, H2, EMBED, EMBED);
  gemm_bt<1><<<dim3(VPAD/128,  MROWS/128), 256, 0, stream>>>(H2, WOT, bout, out, EMBED, VOCAB);
}

// Round 2
// 966.038 us; speedup vs baseline: 1.0174x; 1.0174x over previous
//
#include <hip/hip_runtime.h>
#include <hip/hip_bf16.h>

// Problem constants (fixed by reference)
#define SEQ    2048
#define BATCH  2
#define MROWS  (SEQ*BATCH)    // 4096
#define EMBED  1024
#define KCTX   3
#define XDIM   (KCTX*EMBED)   // 3072
#define VOCAB  50257
#define VPAD   50304          // Wout^T rows allocated (multiple of 128)
#define GK     1024           // K of the logits GEMM
#define NT     (GK/64)        // 16 K-tiles
#define NBLKN  197            // ceil(VOCAB/256)
#define NWG    (16*NBLKN)     // 3152 blocks, divisible by 8

using u16 = unsigned short;
typedef __attribute__((ext_vector_type(8))) short   frag_ab;  // 8 bf16
typedef __attribute__((ext_vector_type(4))) float   frag_cd;  // 4 f32

__device__ __forceinline__ u16 f2bf(float f) {
  union { float f; unsigned u; } v; v.f = f;
  unsigned r = v.u + 0x7fffu + ((v.u >> 16) & 1u);
  return (u16)(r >> 16);
}

__device__ __forceinline__ void gload16(const u16* g, u16* l) {
  __builtin_amdgcn_global_load_lds((const __attribute__((address_space(1))) void*)g,
                                   (__attribute__((address_space(3))) void*)l, 16, 0, 0);
}

// ---------------------------------------------------------------------------
// Gather: XB[r][i*1024+c] = bf16(E[tok(r,i)][c]); r = s*BATCH+b
// ---------------------------------------------------------------------------
__global__ void gather_x(const int* __restrict__ tokens,
                         const float* __restrict__ E,
                         u16* __restrict__ XB) {
  const int r = blockIdx.x;
  const int s = r >> 1, b = r & 1;
  #pragma unroll
  for (int i = 0; i < KCTX; ++i) {
    int t = s + i - (KCTX - 1);
    int tok = (t >= 0) ? tokens[t * BATCH + b] : 0;
    const float* src = &E[(size_t)tok * EMBED];
    u16* dst = &XB[(size_t)r * XDIM + i * EMBED];
    int c = threadIdx.x * 4;
    float4 v = *(const float4*)&src[c];
    u16 o[4] = { f2bf(v.x), f2bf(v.y), f2bf(v.z), f2bf(v.w) };
    *(ulong1*)&dst[c] = *(ulong1*)o;
  }
}

// ---------------------------------------------------------------------------
// Transpose + f32->bf16: W (K x N) -> WT (Npad x K). n >= N writes 0.
// ---------------------------------------------------------------------------
__global__ void transpose_cvt(const float* __restrict__ W,
                              u16* __restrict__ WT,
                              int K, int N) {
  __shared__ float tile[32][33];
  const int nb = blockIdx.x * 32, kb = blockIdx.y * 32;
  const int tx = threadIdx.x & 31, ty = threadIdx.x >> 5;
  #pragma unroll
  for (int i = 0; i < 32; i += 8) {
    int k = kb + ty + i, n = nb + tx;
    tile[ty + i][tx] = (n < N) ? W[(size_t)k * N + n] : 0.f;
  }
  __syncthreads();
  #pragma unroll
  for (int i = 0; i < 32; i += 8) {
    int n = nb + ty + i, k = kb + tx;
    WT[(size_t)n * K + k] = f2bf(tile[tx][ty + i]);
  }
}

// ---------------------------------------------------------------------------
// 128x128-tile GEMM (2-phase) for the two small GEMMs. Verified round 1.
// ---------------------------------------------------------------------------
template<int EPI>
__global__ __launch_bounds__(256, 2)
void gemm_bt(const u16* __restrict__ A, const u16* __restrict__ BT,
             const float* __restrict__ bias, void* __restrict__ Cout,
             int K, int Nout) {
  __shared__ u16 lA[128 * 64];
  __shared__ u16 lB[128 * 64];
  const int tid  = threadIdx.x;
  const int wave = tid >> 6, lane = tid & 63;
  const int m0 = blockIdx.y * 128;
  const int n0 = blockIdx.x * 128;
  const int wm = (wave >> 1) * 64;
  const int wn = (wave & 1) * 64;

  frag_cd acc[4][4];
  #pragma unroll
  for (int i = 0; i < 4; ++i)
    #pragma unroll
    for (int j = 0; j < 4; ++j)
      acc[i][j] = (frag_cd)0.f;

  const int srow = lane >> 3;
  const int skc  = (lane & 7) * 8;

  for (int k0 = 0; k0 < K; k0 += 64) {
    #pragma unroll
    for (int i = 0; i < 4; ++i) {
      int chunk = wave * 4 + i;
      int r = chunk * 8 + srow;
      const u16* ga = &A [(size_t)(m0 + r) * K + k0 + skc];
      const u16* gb = &BT[(size_t)(n0 + r) * K + k0 + skc];
      gload16(ga, &lA[chunk * 512 + lane * 8]);
      gload16(gb, &lB[chunk * 512 + lane * 8]);
    }
    __syncthreads();

    #pragma unroll
    for (int kk = 0; kk < 2; ++kk) {
      const int ko = kk * 32 + (lane >> 4) * 8;
      frag_ab af[4], bfr[4];
      #pragma unroll
      for (int i = 0; i < 4; ++i) {
        af[i]  = *(const frag_ab*)&lA[(wm + i * 16 + (lane & 15)) * 64 + ko];
        bfr[i] = *(const frag_ab*)&lB[(wn + i * 16 + (lane & 15)) * 64 + ko];
      }
      #pragma unroll
      for (int i = 0; i < 4; ++i)
        #pragma unroll
        for (int j = 0; j < 4; ++j)
          acc[i][j] = __builtin_amdgcn_mfma_f32_16x16x32_bf16(
              af[i], bfr[j], acc[i][j], 0, 0, 0);
    }
    __syncthreads();
  }

  const int cr = (lane >> 4) * 4;
  const int cc = lane & 15;
  if (EPI == 0) {
    u16* H = (u16*)Cout;
    #pragma unroll
    for (int j = 0; j < 4; ++j) {
      int colg = n0 + wn + j * 16 + cc;
      float bv = bias[colg];
      #pragma unroll
      for (int i = 0; i < 4; ++i)
        #pragma unroll
        for (int t = 0; t < 4; ++t) {
          int rowg = m0 + wm + i * 16 + cr + t;
          float v = acc[i][j][t] + bv;
          v = v / (1.f + __expf(-v));
          H[(size_t)rowg * Nout + colg] = f2bf(v);
        }
    }
  } else {
    float* O = (float*)Cout;
    #pragma unroll
    for (int j = 0; j < 4; ++j) {
      int colg = n0 + wn + j * 16 + cc;
      if (colg < Nout) {
        float bv = bias[colg];
        #pragma unroll
        for (int i = 0; i < 4; ++i)
          #pragma unroll
          for (int t = 0; t < 4; ++t) {
            int rowg = m0 + wm + i * 16 + cr + t;
            O[(size_t)rowg * Nout + colg] = acc[i][j][t] + bv;
          }
      }
    }
  }
}

// ---------------------------------------------------------------------------
// 256x256-tile 8-phase GEMM for the logits layer (T1+T2+T3+T4+T5).
// A: 4096 x 1024 bf16 (H2). BT: VPAD x 1024 bf16 (Wout^T). O: 4096 x VOCAB f32.
// 8 waves (2M x 4N), 128x64 out/wave, BK=64, 2 K-tile buffers (128 KiB LDS).
// Swizzle: LDS[r][klin] = G[r][klin ^ (r&7)*8] via pre-swizzled global source
// (linear global_load_lds dest) + XOR'd ds_read address.
// K-tile = 4 chunks (A0,B0,B1,A1), staged 1/phase, 2 loads/thread each.
// vmcnt(4) ledger: each chunk has exactly 4 younger loads at its wait point.
// ---------------------------------------------------------------------------
#define BARR   asm volatile("s_barrier" ::: "memory")
#define VMCNT4 asm volatile("s_waitcnt vmcnt(4)" ::: "memory")

#define STAGE2(P0, P1, WBUF, LO0, LO1) { gload16(P0, (WBUF) + (LO0)); gload16(P1, (WBUF) + (LO1)); }

#define RD_A(RBUF, QM) { \
  _Pragma("unroll") for (int i = 0; i < 4; ++i) { \
    aF[i][0] = *(const frag_ab*)((const char*)(RBUF) + aoffB + (QM)*8192 + i*2048 + kb0); \
    aF[i][1] = *(const frag_ab*)((const char*)(RBUF) + aoffB + (QM)*8192 + i*2048 + kb1); \
  } }

#define RD_B(RBUF, QN, BF) { \
  _Pragma("unroll") for (int j = 0; j < 2; ++j) { \
    BF[j][0] = *(const frag_ab*)((const char*)(RBUF) + boffB + (QN)*4096 + j*2048 + kb0); \
    BF[j][1] = *(const frag_ab*)((const char*)(RBUF) + boffB + (QN)*4096 + j*2048 + kb1); \
  } }

#define MFMA_QUAD(QM, QN, BF) { \
  _Pragma("unroll") for (int i = 0; i < 4; ++i) \
  _Pragma("unroll") for (int j = 0; j < 2; ++j) { \
    acc[(QM)*4+i][(QN)*2+j] = __builtin_amdgcn_mfma_f32_16x16x32_bf16(aF[i][0], BF[j][0], acc[(QM)*4+i][(QN)*2+j], 0,0,0); \
    acc[(QM)*4+i][(QN)*2+j] = __builtin_amdgcn_mfma_f32_16x16x32_bf16(aF[i][1], BF[j][1], acc[(QM)*4+i][(QN)*2+j], 0,0,0); \
  } }

#define ADV { pA00+=64; pA01+=64; pA10+=64; pA11+=64; pB00+=64; pB01+=64; pB10+=64; pB11+=64; }

#define KTILE(RA, RB, WA, WB) { \
  /* PH0: stage A0(t+1); read A0,B0; mfma quad(0,0) */ \
  STAGE2(pA00, pA10, WA, loA00, loA10); \
  RD_A(RA, 0); RD_B(RB, 0, b0F); \
  BARR; \
  __builtin_amdgcn_s_setprio(1); MFMA_QUAD(0, 0, b0F); __builtin_amdgcn_s_setprio(0); \
  VMCNT4; BARR; \
  /* PH1: stage B0(t+1); read B1; mfma quad(0,1) */ \
  STAGE2(pB00, pB10, WB, loB00, loB10); \
  RD_B(RB, 1, b1F); \
  BARR; \
  __builtin_amdgcn_s_setprio(1); MFMA_QUAD(0, 1, b1F); __builtin_amdgcn_s_setprio(0); \
  VMCNT4; BARR; \
  /* PH2: stage B1(t+1); read A1; mfma quad(1,1) */ \
  STAGE2(pB01, pB11, WB, loB01, loB11); \
  RD_A(RA, 1); \
  BARR; \
  __builtin_amdgcn_s_setprio(1); MFMA_QUAD(1, 1, b1F); __builtin_amdgcn_s_setprio(0); \
  BARR; \
  /* PH3: stage A1(t+1); mfma quad(1,0) (reuse A1,B0 regs) */ \
  STAGE2(pA01, pA11, WA, loA01, loA11); \
  BARR; \
  __builtin_amdgcn_s_setprio(1); MFMA_QUAD(1, 0, b0F); __builtin_amdgcn_s_setprio(0); \
  VMCNT4; BARR; \
}

__global__ __launch_bounds__(512, 2)
void gemm256(const u16* __restrict__ A, const u16* __restrict__ BT,
             const float* __restrict__ bias, float* __restrict__ O) {
  extern __shared__ char smraw[];
  u16* tA0 = (u16*)smraw;               // 256x64 bf16 = 32 KiB each
  u16* tA1 = (u16*)(smraw + 32768);
  u16* tB0 = (u16*)(smraw + 65536);
  u16* tB1 = (u16*)(smraw + 98304);

  // Bijective chunked XCD swizzle; M-innermost so one XCD reuses one B-panel.
  const int bid = blockIdx.x;
  const int wg  = (bid & 7) * (NWG / 8) + (bid >> 3);
  const int m0  = (wg & 15) * 256;
  const int n0  = (wg >> 4) * 256;

  const int tid  = threadIdx.x;
  const int lane = tid & 63, wave = tid >> 6;
  const int wm = wave >> 2, wn = wave & 3;   // 2 x 4 waves

  // ---- staging constants (2 load slots: f0=tid, f1=tid+512; ks identical) --
  const int rc0 = tid >> 3, ks0 = tid & 7;                // rc0 0..63
  const int ke0 = (ks0 ^ (rc0 & 7)) * 8;                  // pre-swizzled k elems
  // A chunk rows: qm0:{rc0, rc0+128}, qm1:{rc0+64, rc0+192}
  // B chunk rows: base rB = (rc0>>5)*64 + (rc0&31); qn1:+32; slot1:+128
  const int rB = (rc0 >> 5) * 64 + (rc0 & 31);
  const int loA00 = rc0 * 64 + ks0 * 8;
  const int loA01 = loA00 + 64 * 64;     // +64 rows
  const int loA10 = loA00 + 128 * 64;
  const int loA11 = loA00 + 192 * 64;
  const int loB00 = rB * 64 + ks0 * 8;
  const int loB01 = loB00 + 32 * 64;
  const int loB10 = loB00 + 128 * 64;
  const int loB11 = loB00 + 160 * 64;

  int rb00 = n0 + rB;        if (rb00 > VPAD - 1) rb00 = VPAD - 1;
  int rb01 = n0 + rB + 32;   if (rb01 > VPAD - 1) rb01 = VPAD - 1;
  int rb10 = n0 + rB + 128;  if (rb10 > VPAD - 1) rb10 = VPAD - 1;
  int rb11 = n0 + rB + 160;  if (rb11 > VPAD - 1) rb11 = VPAD - 1;

  const u16 *pA00 = A + (size_t)(m0 + rc0      ) * GK + ke0;
  const u16 *pA01 = A + (size_t)(m0 + rc0 +  64) * GK + ke0;
  const u16 *pA10 = A + (size_t)(m0 + rc0 + 128) * GK + ke0;
  const u16 *pA11 = A + (size_t)(m0 + rc0 + 192) * GK + ke0;
  const u16 *pB00 = BT + (size_t)rb00 * GK + ke0;
  const u16 *pB01 = BT + (size_t)rb01 * GK + ke0;
  const u16 *pB10 = BT + (size_t)rb10 * GK + ke0;
  const u16 *pB11 = BT + (size_t)rb11 * GK + ke0;

  // ---- ds_read constants (XOR-swizzled k byte offsets; row&7 == lane&7) ----
  const int kb0 = (((lane >> 4) * 16)      ) ^ ((lane & 7) << 4);
  const int kb1 = (((lane >> 4) * 16) + 64 ) ^ ((lane & 7) << 4);
  const int aoffB = (wm * 128 + (lane & 15)) * 128;   // bytes
  const int boffB = (wn * 64  + (lane & 15)) * 128;

  frag_ab aF[4][2], b0F[2][2], b1F[2][2];
  frag_cd acc[8][4];
  #pragma unroll
  for (int i = 0; i < 8; ++i)
    #pragma unroll
    for (int j = 0; j < 4; ++j)
      acc[i][j] = (frag_cd)0.f;

  // ---- prologue: stage K-tile 0 (chunk order A0,B0,B1,A1) into buf0 ----
  STAGE2(pA00, pA10, tA0, loA00, loA10);
  STAGE2(pB00, pB10, tB0, loB00, loB10);
  STAGE2(pB01, pB11, tB0, loB01, loB11);
  STAGE2(pA01, pA11, tA0, loA01, loA11);
  ADV;
  VMCNT4; BARR;   // A0,B0 of tile 0 landed (own) + cross-wave seal

  // ---- main loop: 16 K-tiles, double-buffered ----
  #pragma unroll 1
  for (int tt = 0; tt < NT / 2; ++tt) {
    KTILE(tA0, tB0, tA1, tB1);
    ADV;
    KTILE(tA1, tB1, tA0, tB0);
    ADV;
  }

  asm volatile("s_waitcnt vmcnt(0) lgkmcnt(0)" ::: "memory");

  // ---- epilogue: bias + f32 store, col guard ----
  const int cr = (lane >> 4) * 4;
  const int cc = lane & 15;
  #pragma unroll
  for (int fj = 0; fj < 4; ++fj) {
    int colg = n0 + wn * 64 + fj * 16 + cc;
    if (colg < VOCAB) {
      float bv = bias[colg];
      #pragma unroll
      for (int fi = 0; fi < 8; ++fi)
        #pragma unroll
        for (int t = 0; t < 4; ++t) {
          int rowg = m0 + wm * 128 + fi * 16 + cr + t;
          O[(size_t)rowg * VOCAB + colg] = acc[fi][fj][t] + bv;
        }
    }
  }
}

// ---------------------------------------------------------------------------
extern "C" void kernel_launch(void* const* d_in, const int* in_sizes, int n_in,
                              void* d_out, int out_size, void* d_ws, size_t ws_size,
                              hipStream_t stream) {
  const int*   tokens = (const int*)  d_in[0];
  const float* E      = (const float*)d_in[1];
  const float* W1     = (const float*)d_in[2];
  const float* b1     = (const float*)d_in[3];
  const float* W2     = (const float*)d_in[4];
  const float* b2     = (const float*)d_in[5];
  const float* Wout   = (const float*)d_in[6];
  const float* bout   = (const float*)d_in[7];
  float* out = (float*)d_out;

  // Workspace layout (~153.4 MB). Order chosen so gemm256's harmless
  // last-tile over-advance reads (<=142 B past H2 / WOT) land inside ws.
  char* p = (char*)d_ws;
  u16* XB  = (u16*)p; p += (size_t)MROWS * XDIM  * 2;   // 25.2 MB
  u16* WOT = (u16*)p; p += (size_t)VPAD  * EMBED * 2;   // 103.0 MB (over-read -> H1)
  u16* H1  = (u16*)p; p += (size_t)MROWS * EMBED * 2;   //  8.4 MB
  u16* H2  = (u16*)p; p += (size_t)MROWS * EMBED * 2;   //  8.4 MB (over-read -> W1T)
  u16* W1T = (u16*)p; p += (size_t)EMBED * XDIM  * 2;   //  6.3 MB
  u16* W2T = (u16*)p; p += (size_t)EMBED * EMBED * 2;   //  2.1 MB

  hipFuncSetAttribute((const void*)gemm256,
                      hipFuncAttributeMaxDynamicSharedMemorySize, 131072);

  gather_x<<<MROWS, 256, 0, stream>>>(tokens, E, XB);
  transpose_cvt<<<dim3(EMBED/32, XDIM/32),  256, 0, stream>>>(W1,   W1T, XDIM,  EMBED);
  transpose_cvt<<<dim3(EMBED/32, EMBED/32), 256, 0, stream>>>(W2,   W2T, EMBED, EMBED);
  transpose_cvt<<<dim3(VPAD/32,  EMBED/32), 256, 0, stream>>>(Wout, WOT, EMBED, VOCAB);

  gemm_bt<0><<<dim3(EMBED/128, MROWS/128), 256, 0, stream>>>(XB, W1T, b1, H1, XDIM,  EMBED);
  gemm_bt<0><<<dim3(EMBED/128, MROWS/128), 256, 0, stream>>>(H1, W2T, b2, H2, EMBED, EMBED);
  gemm256<<<NWG, 512, 131072, stream>>>(H2, WOT, bout, out);
}